// Round 17
// baseline (466.918 us; speedup 1.0000x reference)
//
#include <hip/hip_runtime.h>
#include <cstdint>
#include <cstddef>

// Problem constants: B=4, T=2048, C=1024, H=16, d=64
#define T_SEQ 2048
#define CEMB  1024
#define NHEAD 16
#define DHEAD 64

// q pre-scale: 32 (sqrt(C) quirk) * log2(e)  -> logits in log2 units
#define QSCALE 46.1662413084468f

typedef __attribute__((ext_vector_type(8))) short bf16x8;
typedef __attribute__((ext_vector_type(4))) float f32x4;

static __device__ __forceinline__ unsigned short f2bf(float x) {
    unsigned u = __builtin_bit_cast(unsigned, x);
    unsigned r = (u + 0x7FFFu + ((u >> 16) & 1u)) >> 16;
    return (unsigned short)r;
}
static __device__ __forceinline__ float bf2f(unsigned short b) {
    unsigned u = ((unsigned)b) << 16;
    return __builtin_bit_cast(float, u);
}

// async global->LDS: 16B per lane; ldsbase wave-uniform, lane offset = lane*16B.
static __device__ __forceinline__ void gload16(const short* gsrc, short* ldsbase) {
    __builtin_amdgcn_global_load_lds(
        (const __attribute__((address_space(1))) void*)gsrc,
        (__attribute__((address_space(3))) void*)ldsbase, 16, 0, 0);
}

// ---------------------------------------------------------------------------
// QK split-GEMM (R13 structure): 128x128 tile, BK=32, 256 threads.
// A = x fp32, split hi/lo in staging (VALU). B pre-split. 3 MFMAs (hh+lh+hl).
// R17: __launch_bounds__(256,5) -> VGPR<=102 -> 5 blocks/CU (LDS 5x32KB=160KB).
// Output: split hi/lo bf16, q cols (<1024) pre-scaled by QSCALE.
// LDS shorts: A_hi @0, B_hi @4096, A_lo @8192, B_lo @12288.
// ---------------------------------------------------------------------------
__global__ __launch_bounds__(256, 5) void gemm_qk_kernel(
    const float* __restrict__ Af,
    const short* __restrict__ Bh, const short* __restrict__ Bl,
    const float* __restrict__ bias,
    short* __restrict__ Chi, short* __restrict__ Clo, int K)
{
    __shared__ __align__(16) short smem[16384];

    const int tid = threadIdx.x;
    const int w = tid >> 6, l = tid & 63;
    const int lr = l & 15, lg = l >> 4;
    const int wr = w >> 1, wc = w & 1;
    const int row0 = blockIdx.y * 128;
    const int col0 = blockIdx.x * 128;

    f32x4 acc[4][4];
    #pragma unroll
    for (int mt = 0; mt < 4; ++mt)
        #pragma unroll
        for (int nt = 0; nt < 4; ++nt)
            acc[mt][nt] = (f32x4){0.f, 0.f, 0.f, 0.f};

    const int sB0 = w * 128 + l, sB1 = sB0 + 64;
    const size_t bO0 = (size_t)(col0 + (sB0 & 127)) * K + (sB0 >> 7) * 8;
    const size_t bO1 = (size_t)(col0 + (sB1 & 127)) * K + (sB1 >> 7) * 8;
    const short* gB0  = Bh + bO0;  const short* gB1  = Bh + bO1;
    const short* gBl0 = Bl + bO0;  const short* gBl1 = Bl + bO1;
    short* const dB0 = &smem[4096 + (w * 128) * 8];
    short* const dB1 = &smem[4096 + (w * 128 + 64) * 8];

    const int arow = tid >> 1, ahalf = tid & 1;
    const float* gAf = Af + (size_t)(row0 + arow) * K + ahalf * 16;

    for (int kt = 0; kt < K; kt += 32) {
        __syncthreads();
        gload16(gB0 + kt, dB0);
        gload16(gB1 + kt, dB1);
        gload16(gBl0 + kt, dB0 + 8192);   // -> 12288 region
        gload16(gBl1 + kt, dB1 + 8192);
        {
            const float* src = gAf + kt;
            float4 f0 = *(const float4*)(src);
            float4 f1 = *(const float4*)(src + 4);
            float4 f2 = *(const float4*)(src + 8);
            float4 f3 = *(const float4*)(src + 12);
            float xs[16] = {f0.x, f0.y, f0.z, f0.w, f1.x, f1.y, f1.z, f1.w,
                            f2.x, f2.y, f2.z, f2.w, f3.x, f3.y, f3.z, f3.w};
            #pragma unroll
            for (int q = 0; q < 2; ++q) {
                bf16x8 h8, l8;
                #pragma unroll
                for (int e = 0; e < 8; ++e) {
                    float x = xs[q * 8 + e];
                    unsigned u = __builtin_bit_cast(unsigned, x);
                    h8[e] = (short)(unsigned short)(u >> 16);
                    float hf = __builtin_bit_cast(float, u & 0xFFFF0000u);
                    l8[e] = (short)f2bf(x - hf);
                }
                int slot = (ahalf * 2 + q) * 128 + arow;
                *(bf16x8*)&smem[slot * 8] = h8;
                *(bf16x8*)&smem[8192 + slot * 8] = l8;
            }
        }
        __syncthreads();

        const int ao = (lg * 128 + wr * 64 + lr) * 8;
        const int bo = 4096 + (lg * 128 + wc * 64 + lr) * 8;
        bf16x8 ahf[4], alf[4];
        #pragma unroll
        for (int mt = 0; mt < 4; ++mt) {
            ahf[mt] = *(const bf16x8*)&smem[ao + mt * 128];
            alf[mt] = *(const bf16x8*)&smem[8192 + ao + mt * 128];
        }
        #pragma unroll
        for (int nt = 0; nt < 4; ++nt) {
            bf16x8 bhf = *(const bf16x8*)&smem[bo + nt * 128];
            bf16x8 blf = *(const bf16x8*)&smem[8192 + bo + nt * 128];
            #pragma unroll
            for (int mt = 0; mt < 4; ++mt) {
                acc[mt][nt] = __builtin_amdgcn_mfma_f32_16x16x32_bf16(ahf[mt], bhf, acc[mt][nt], 0, 0, 0);
                acc[mt][nt] = __builtin_amdgcn_mfma_f32_16x16x32_bf16(alf[mt], bhf, acc[mt][nt], 0, 0, 0);
                acc[mt][nt] = __builtin_amdgcn_mfma_f32_16x16x32_bf16(ahf[mt], blf, acc[mt][nt], 0, 0, 0);
            }
        }
    }

    #pragma unroll
    for (int mt = 0; mt < 4; ++mt) {
        #pragma unroll
        for (int r = 0; r < 4; ++r) {
            int m = row0 + wr * 64 + mt * 16 + lg * 4 + r;
            #pragma unroll
            for (int nt = 0; nt < 4; ++nt) {
                int n = col0 + wc * 64 + nt * 16 + lr;
                float v = acc[mt][nt][r] + bias[n];
                if (n < 1024) v *= QSCALE;
                unsigned u = __builtin_bit_cast(unsigned, v);
                Chi[(size_t)m * 2048 + n] = (short)(unsigned short)(u >> 16);
                float hf = __builtin_bit_cast(float, u & 0xFFFF0000u);
                Clo[(size_t)m * 2048 + n] = (short)f2bf(v - hf);
            }
        }
    }
}

// ---------------------------------------------------------------------------
// V-GEMM (R13 config): A = x fp32 (RNE->bf16 in staging), B bf16; transposed
// epilogue writes Vt[B][H][64][T] directly (no repack kernel).
// ---------------------------------------------------------------------------
__global__ __launch_bounds__(256) void gemm_v_kernel(
    const float* __restrict__ Af, const short* __restrict__ Bh,
    const float* __restrict__ bias, short* __restrict__ vt, int K)
{
    __shared__ __align__(16) short smem[17408];   // staging 8192; epilogue 128*136

    const int tid = threadIdx.x;
    const int w = tid >> 6, l = tid & 63;
    const int lr = l & 15, lg = l >> 4;
    const int wr = w >> 1, wc = w & 1;
    const int row0 = blockIdx.y * 128;
    const int col0 = blockIdx.x * 128;

    f32x4 acc[4][4];
    #pragma unroll
    for (int mt = 0; mt < 4; ++mt)
        #pragma unroll
        for (int nt = 0; nt < 4; ++nt)
            acc[mt][nt] = (f32x4){0.f, 0.f, 0.f, 0.f};

    const int sB0 = w * 128 + l, sB1 = sB0 + 64;
    const size_t bO0 = (size_t)(col0 + (sB0 & 127)) * K + (sB0 >> 7) * 8;
    const size_t bO1 = (size_t)(col0 + (sB1 & 127)) * K + (sB1 >> 7) * 8;
    const short* gB0 = Bh + bO0;  const short* gB1 = Bh + bO1;
    short* const dB0 = &smem[4096 + (w * 128) * 8];
    short* const dB1 = &smem[4096 + (w * 128 + 64) * 8];

    const int arow = tid >> 1, ahalf = tid & 1;
    const float* gAf = Af + (size_t)(row0 + arow) * K + ahalf * 16;

    for (int kt = 0; kt < K; kt += 32) {
        __syncthreads();
        gload16(gB0 + kt, dB0);
        gload16(gB1 + kt, dB1);
        {
            const float* src = gAf + kt;
            float4 f0 = *(const float4*)(src);
            float4 f1 = *(const float4*)(src + 4);
            float4 f2 = *(const float4*)(src + 8);
            float4 f3 = *(const float4*)(src + 12);
            float xs[16] = {f0.x, f0.y, f0.z, f0.w, f1.x, f1.y, f1.z, f1.w,
                            f2.x, f2.y, f2.z, f2.w, f3.x, f3.y, f3.z, f3.w};
            #pragma unroll
            for (int q = 0; q < 2; ++q) {
                bf16x8 h8;
                #pragma unroll
                for (int e = 0; e < 8; ++e) h8[e] = (short)f2bf(xs[q * 8 + e]);
                int slot = (ahalf * 2 + q) * 128 + arow;
                *(bf16x8*)&smem[slot * 8] = h8;
            }
        }
        __syncthreads();

        const int ao = (lg * 128 + wr * 64 + lr) * 8;
        const int bo = 4096 + (lg * 128 + wc * 64 + lr) * 8;
        bf16x8 ahf[4];
        #pragma unroll
        for (int mt = 0; mt < 4; ++mt)
            ahf[mt] = *(const bf16x8*)&smem[ao + mt * 128];
        #pragma unroll
        for (int nt = 0; nt < 4; ++nt) {
            bf16x8 bhf = *(const bf16x8*)&smem[bo + nt * 128];
            #pragma unroll
            for (int mt = 0; mt < 4; ++mt)
                acc[mt][nt] = __builtin_amdgcn_mfma_f32_16x16x32_bf16(ahf[mt], bhf, acc[mt][nt], 0, 0, 0);
        }
    }

    // ---- transposed epilogue: acc -> smem[n_local][t_local] (pad 136) ----
    __syncthreads();
    #pragma unroll
    for (int mt = 0; mt < 4; ++mt) {
        const int tb = wr * 64 + mt * 16 + lg * 4;
        #pragma unroll
        for (int nt = 0; nt < 4; ++nt) {
            const int nl = wc * 64 + nt * 16 + lr;
            float bv = bias[col0 + nl];
            unsigned u0 = (unsigned)f2bf(acc[mt][nt][0] + bv) |
                          ((unsigned)f2bf(acc[mt][nt][1] + bv) << 16);
            unsigned u1 = (unsigned)f2bf(acc[mt][nt][2] + bv) |
                          ((unsigned)f2bf(acc[mt][nt][3] + bv) << 16);
            uint2 uu; uu.x = u0; uu.y = u1;
            *(uint2*)&smem[nl * 136 + tb] = uu;
        }
    }
    __syncthreads();

    const int b  = row0 >> 11;
    const int t0 = row0 & 2047;
    #pragma unroll
    for (int i = 0; i < 8; ++i) {
        int nl = (tid >> 4) + i * 16;
        int t8 = (tid & 15) * 8;
        bf16x8 vv = *(const bf16x8*)&smem[nl * 136 + t8];
        int n = col0 + nl;
        int hh = n >> 6, d = n & 63;
        short* dst = vt + ((size_t)((b * NHEAD + hh) * DHEAD + d)) * T_SEQ + t0 + t8;
        *(bf16x8*)dst = vv;
    }
}

// ---------------------------------------------------------------------------
// Proj GEMM, R17: 128x64 tile (grid 16x64 = 1024 blocks ~ 4+/CU), BK=32,
// counted-vmcnt double-buffer (3-issue stage, vmcnt(3) mid-loop).
// LDS per buf: A[4][128][8] (4096 sh) + B[4][64][8] (2048 sh); 2 bufs = 24 KB.
// ---------------------------------------------------------------------------
__global__ __launch_bounds__(256) void gemm_proj_kernel(
    const short* __restrict__ Ah, const short* __restrict__ Bh,
    const float* __restrict__ bias, float* __restrict__ Cout, int K, int ldc)
{
    __shared__ __align__(16) short smem[12288];   // 2 x 6144 shorts

    const int tid = threadIdx.x;
    const int w = tid >> 6, l = tid & 63;
    const int lr = l & 15, lg = l >> 4;
    const int wr = w >> 1, wc = w & 1;
    const int row0 = blockIdx.y * 128;
    const int col0 = blockIdx.x * 64;

    f32x4 acc[4][2];
    #pragma unroll
    for (int mt = 0; mt < 4; ++mt)
        #pragma unroll
        for (int nt = 0; nt < 2; ++nt)
            acc[mt][nt] = (f32x4){0.f, 0.f, 0.f, 0.f};

    // A staging: granules s0 = w*128+l, s1 = s0+64 (512 total, rows 0..127 x 4 kc)
    const int s0 = w * 128 + l, s1 = s0 + 64;
    const size_t aoff0 = (size_t)(row0 + (s0 & 127)) * K + (s0 >> 7) * 8;
    const size_t aoff1 = (size_t)(row0 + (s1 & 127)) * K + (s1 >> 7) * 8;
    // B staging: granule tid (256 total: rows 0..63 x 4 kc)
    const size_t boff = (size_t)(col0 + (tid & 63)) * K + (tid >> 6) * 8;
    const short* gA0 = Ah + aoff0;  const short* gA1 = Ah + aoff1;
    const short* gB  = Bh + boff;
    short* const dA0 = &smem[(w * 128) * 8];
    short* const dA1 = &smem[(w * 128 + 64) * 8];
    short* const dB  = &smem[4096 + (w * 64) * 8];

    #define PSTAGE(buf, kt) do {                      \
        gload16(gA0 + (kt), dA0 + (buf) * 6144);      \
        gload16(gA1 + (kt), dA1 + (buf) * 6144);      \
        gload16(gB  + (kt), dB  + (buf) * 6144);      \
    } while (0)

    const int nkt = K / 32;
    PSTAGE(0, 0);
    for (int ti = 0; ti < nkt; ++ti) {
        if (ti + 1 < nkt) {
            PSTAGE((ti + 1) & 1, (ti + 1) * 32);
            asm volatile("s_waitcnt vmcnt(3)" ::: "memory");
        } else {
            asm volatile("s_waitcnt vmcnt(0)" ::: "memory");
        }
        __builtin_amdgcn_s_barrier();
        __builtin_amdgcn_sched_barrier(0);

        const int sb = (ti & 1) * 6144;
        const int ao = sb + (lg * 128 + wr * 64 + lr) * 8;
        const int bo = sb + 4096 + (lg * 64 + wc * 32 + lr) * 8;
        bf16x8 ahf[4];
        #pragma unroll
        for (int mt = 0; mt < 4; ++mt)
            ahf[mt] = *(const bf16x8*)&smem[ao + mt * 128];
        #pragma unroll
        for (int nt = 0; nt < 2; ++nt) {
            bf16x8 bhf = *(const bf16x8*)&smem[bo + nt * 128];
            #pragma unroll
            for (int mt = 0; mt < 4; ++mt)
                acc[mt][nt] = __builtin_amdgcn_mfma_f32_16x16x32_bf16(ahf[mt], bhf, acc[mt][nt], 0, 0, 0);
        }
        __builtin_amdgcn_sched_barrier(0);
        __builtin_amdgcn_s_barrier();
        __builtin_amdgcn_sched_barrier(0);
    }
    #undef PSTAGE

    #pragma unroll
    for (int mt = 0; mt < 4; ++mt) {
        #pragma unroll
        for (int r = 0; r < 4; ++r) {
            int m = row0 + wr * 64 + mt * 16 + lg * 4 + r;
            #pragma unroll
            for (int nt = 0; nt < 2; ++nt) {
                int n = col0 + wc * 32 + nt * 16 + lr;
                Cout[(size_t)m * ldc + n] = acc[mt][nt][r] + bias[n];
            }
        }
    }
}

// ---------------------------------------------------------------------------
// Transpose + hi/lo bf16 split: src fp32 [Krows][nsrc] -> hi/lo [N][1024]
// ---------------------------------------------------------------------------
__global__ __launch_bounds__(256) void transpose_split_kernel(
    const float* __restrict__ src, int nsrc,
    short* __restrict__ hi, short* __restrict__ lo)
{
    __shared__ float tile[64][68];
    const int tid = threadIdx.x;
    const int n0 = blockIdx.x * 64, k0 = blockIdx.y * 64;
    {
        int kr = tid >> 2, cg = tid & 3;
        const float* s = src + (size_t)(k0 + kr) * nsrc + n0 + cg * 16;
        #pragma unroll
        for (int q = 0; q < 4; ++q) {
            float4 f = *(const float4*)(s + q * 4);
            tile[kr][cg * 16 + q * 4 + 0] = f.x;
            tile[kr][cg * 16 + q * 4 + 1] = f.y;
            tile[kr][cg * 16 + q * 4 + 2] = f.z;
            tile[kr][cg * 16 + q * 4 + 3] = f.w;
        }
    }
    __syncthreads();
    {
        int nr = tid >> 2, kg = tid & 3;
        int n = n0 + nr;
        bf16x8 h0, h1, lo0, lo1;
        #pragma unroll
        for (int e = 0; e < 8; ++e) {
            float a = tile[kg * 16 + e][nr];
            float b = tile[kg * 16 + 8 + e][nr];
            unsigned short ha = f2bf(a), hb = f2bf(b);
            h0[e] = (short)ha; h1[e] = (short)hb;
            lo0[e] = (short)f2bf(a - bf2f(ha));
            lo1[e] = (short)f2bf(b - bf2f(hb));
        }
        short* dh = hi + (size_t)n * 1024 + k0 + kg * 16;
        *(bf16x8*)dh = h0;
        *(bf16x8*)(dh + 8) = h1;
        if (lo) {
            short* dl = lo + (size_t)n * 1024 + k0 + kg * 16;
            *(bf16x8*)dl = lo0;
            *(bf16x8*)(dl + 8) = lo1;
        }
    }
}

// ---------------------------------------------------------------------------
// MFMA flash attention (causal), swapped QK^T + counted-vmcnt V-dbuf pipeline
// + early-K issue (R15-validated). Unchanged from R16.
// ---------------------------------------------------------------------------
__global__ __launch_bounds__(256) void attn_mfma_kernel(
    const short* __restrict__ qkhi, const short* __restrict__ qklo,
    const short* __restrict__ vt, short* __restrict__ ctxb)
{
    __shared__ __align__(16) short smem[20480];   // 40960 B

    const int tid = threadIdx.x;
    const int w = tid >> 6, l = tid & 63;
    const int lr = l & 15, lg = l >> 4;

    const int bid = blockIdx.x;
    const int p  = bid >> 6;
    const int bh = bid & 63;
    const int h = bh & 15, b = bh >> 4;
    const size_t bT = (size_t)b * T_SEQ;

    const int g0 = w * 128 + l, g1 = g0 + 64;
    const int rg0 = g0 >> 3, rg1 = g1 >> 3;
    const int sc0 = (g0 & 7) ^ (rg0 & 7), sc1 = (g1 & 7) ^ (rg1 & 7);
    short* const dK0 = &smem[(w * 128) * 8];
    short* const dK1 = &smem[(w * 128 + 64) * 8];

    const size_t koff0 = (bT + rg0) * 2048 + 1024 + h * DHEAD + sc0 * 8;
    const size_t koff1 = (bT + rg1) * 2048 + 1024 + h * DHEAD + sc1 * 8;
    const short* const pKh0 = qkhi + koff0;
    const short* const pKh1 = qkhi + koff1;
    const short* const pKl0 = qklo + koff0;
    const short* const pKl1 = qklo + koff1;
    const short* const pV0 = vt + ((size_t)((b * NHEAD + h) * DHEAD) + rg0) * T_SEQ + sc0 * 8;
    const short* const pV1 = vt + ((size_t)((b * NHEAD + h) * DHEAD) + rg1) * T_SEQ + sc1 * 8;

    const int psBase = 16384 + w * 1024;
    const int pwChunk = (lg >> 1);
    const int pwIntra = (lg & 1) * 4;

    for (int half = 0; half < 2; ++half) {
        const int xi = half ? (31 - p) : p;
        const int qw = xi * 64 + w * 16;
        const int nsteps = xi + 1;

        __syncthreads();

        bf16x8 qhi[2], qlo[2];
        #pragma unroll
        for (int kk = 0; kk < 2; ++kk) {
            size_t off = (bT + qw + lr) * 2048 + h * DHEAD + kk * 32 + lg * 8;
            qhi[kk] = *(const bf16x8*)(qkhi + off);
            qlo[kk] = *(const bf16x8*)(qklo + off);
        }
        __builtin_amdgcn_sched_barrier(0);

        gload16(pKh0, dK0);
        gload16(pKh1, dK1);
        gload16(pKl0, dK0 + 4096);
        gload16(pKl1, dK1 + 4096);
        gload16(pV0, dK0 + 8192);
        gload16(pV1, dK1 + 8192);
        {
            int j1 = (nsteps > 1) ? 64 : 0;
            gload16(pV0 + j1, dK0 + 12288);
            gload16(pV1 + j1, dK1 + 12288);
        }

        f32x4 O[4];
        #pragma unroll
        for (int dt = 0; dt < 4; ++dt)
            O[dt] = (f32x4){0.f, 0.f, 0.f, 0.f};
        float mrow = -3.0e38f;
        float lrow = 0.f;

        for (int t = 0; t < nsteps; ++t) {
            const int j0 = t * 64;
            asm volatile("s_waitcnt vmcnt(2)" ::: "memory");
            __builtin_amdgcn_s_barrier();
            __builtin_amdgcn_sched_barrier(0);
            const int vbase = 8192 + (t & 1) * 4096;

            f32x4 St[4];
            __builtin_amdgcn_s_setprio(1);
            #pragma unroll
            for (int ct = 0; ct < 4; ++ct) {
                f32x4 s = (f32x4){0.f, 0.f, 0.f, 0.f};
                #pragma unroll
                for (int kk = 0; kk < 2; ++kk) {
                    int j  = ct * 16 + lr;
                    int ck = kk * 4 + lg;
                    int idx = j * 64 + ((ck ^ (j & 7)) << 3);
                    bf16x8 kh8 = *(bf16x8*)&smem[idx];
                    bf16x8 kl8 = *(bf16x8*)&smem[4096 + idx];
                    s = __builtin_amdgcn_mfma_f32_16x16x32_bf16(kh8, qhi[kk], s, 0, 0, 0);
                    s = __builtin_amdgcn_mfma_f32_16x16x32_bf16(kh8, qlo[kk], s, 0, 0, 0);
                    s = __builtin_amdgcn_mfma_f32_16x16x32_bf16(kl8, qhi[kk], s, 0, 0, 0);
                }
                St[ct] = s;
            }
            __builtin_amdgcn_s_setprio(0);
            __builtin_amdgcn_sched_barrier(0);
            __builtin_amdgcn_s_barrier();      // all waves' K ds_reads complete
            __builtin_amdgcn_sched_barrier(0);
            if (t + 1 < nsteps) {              // early K(t+1): flies under SM+PV
                size_t ko = (size_t)(t + 1) * 131072;
                gload16(pKh0 + ko, dK0);
                gload16(pKh1 + ko, dK1);
                gload16(pKl0 + ko, dK0 + 4096);
                gload16(pKl1 + ko, dK1 + 4096);
            }

            #pragma unroll
            for (int ct = 0; ct < 4; ++ct) {
                if (j0 + ct * 16 + 15 > qw) {
                    #pragma unroll
                    for (int r = 0; r < 4; ++r) {
                        int jabs = j0 + ct * 16 + lg * 4 + r;
                        St[ct][r] = (jabs <= qw + lr) ? St[ct][r] : -3.0e38f;
                    }
                }
            }

            float tm = fmaxf(fmaxf(fmaxf(St[0][0], St[0][1]), fmaxf(St[0][2], St[0][3])),
                             fmaxf(fmaxf(St[1][0], St[1][1]), fmaxf(St[1][2], St[1][3])));
            tm = fmaxf(tm, fmaxf(fmaxf(fmaxf(St[2][0], St[2][1]), fmaxf(St[2][2], St[2][3])),
                                 fmaxf(fmaxf(St[3][0], St[3][1]), fmaxf(St[3][2], St[3][3]))));
            tm = fmaxf(tm, __shfl_xor(tm, 16));
            tm = fmaxf(tm, __shfl_xor(tm, 32));

            if (__any(tm > mrow)) {
                float mnew  = fmaxf(mrow, tm);
                float alpha = __builtin_amdgcn_exp2f(mrow - mnew);
                mrow = mnew;
                lrow *= alpha;
                #pragma unroll
                for (int r = 0; r < 4; ++r) {
                    float aO = __shfl(alpha, lg * 4 + r);
                    #pragma unroll
                    for (int dt = 0; dt < 4; ++dt)
                        O[dt][r] *= aO;
                }
            }

            #pragma unroll
            for (int ct = 0; ct < 4; ++ct) {
                float p0 = __builtin_amdgcn_exp2f(St[ct][0] - mrow);
                float p1 = __builtin_amdgcn_exp2f(St[ct][1] - mrow);
                float p2 = __builtin_amdgcn_exp2f(St[ct][2] - mrow);
                float p3 = __builtin_amdgcn_exp2f(St[ct][3] - mrow);
                lrow += (p0 + p1) + (p2 + p3);
                unsigned u0 = (__builtin_bit_cast(unsigned, p0) >> 16) |
                              (__builtin_bit_cast(unsigned, p1) & 0xFFFF0000u);
                unsigned u1 = (__builtin_bit_cast(unsigned, p2) >> 16) |
                              (__builtin_bit_cast(unsigned, p3) & 0xFFFF0000u);
                int chunk = ct * 2 + pwChunk;
                int sidx = psBase + lr * 64 + ((chunk ^ (lr & 7)) << 3) + pwIntra;
                uint2 uu; uu.x = u0; uu.y = u1;
                *(uint2*)&smem[sidx] = uu;
            }

            __builtin_amdgcn_wave_barrier();

            bf16x8 pa[2];
            #pragma unroll
            for (int jk = 0; jk < 2; ++jk) {
                int ck = jk * 4 + lg;
                pa[jk] = *(bf16x8*)&smem[psBase + lr * 64 + ((ck ^ (lr & 7)) << 3)];
            }
            __builtin_amdgcn_s_setprio(1);
            #pragma unroll
            for (int dt = 0; dt < 4; ++dt) {
                #pragma unroll
                for (int jk = 0; jk < 2; ++jk) {
                    int d  = dt * 16 + lr;
                    int ck = jk * 4 + lg;
                    bf16x8 vb = *(bf16x8*)&smem[vbase + d * 64 + ((ck ^ (d & 7)) << 3)];
                    O[dt] = __builtin_amdgcn_mfma_f32_16x16x32_bf16(pa[jk], vb, O[dt], 0, 0, 0);
                }
            }
            __builtin_amdgcn_s_setprio(0);

            __builtin_amdgcn_sched_barrier(0);
            __builtin_amdgcn_s_barrier();      // all PV reads of V(t) done
            __builtin_amdgcn_sched_barrier(0);

            if (t + 1 < nsteps) {              // V(t+2) into buf (t&1)
                int jv = (t + 2 < nsteps) ? (t + 2) : (nsteps - 1);
                short* const dV = &smem[8192 + (t & 1) * 4096];
                gload16(pV0 + jv * 64, dV + (w * 128) * 8);
                gload16(pV1 + jv * 64, dV + (w * 128 + 64) * 8);
            }
        }

        float lsum = lrow + __shfl_xor(lrow, 16);
        lsum += __shfl_xor(lsum, 32);
        #pragma unroll
        for (int r = 0; r < 4; ++r) {
            float lO = __shfl(lsum, lg * 4 + r);
            float inv = 1.0f / lO;
            int row = qw + lg * 4 + r;
            #pragma unroll
            for (int dt = 0; dt < 4; ++dt) {
                int col = h * DHEAD + dt * 16 + lr;
                ctxb[(size_t)(b * T_SEQ + row) * CEMB + col] = (short)f2bf(O[dt][r] * inv);
            }
        }
    }
}

// ---------------------------------------------------------------------------
extern "C" void kernel_launch(void* const* d_in, const int* in_sizes, int n_in,
                              void* d_out, int out_size, void* d_ws, size_t ws_size,
                              hipStream_t stream)
{
    const float* x    = (const float*)d_in[0];
    const float* Wqkv = (const float*)d_in[1];
    const float* bqkv = (const float*)d_in[2];
    const float* Wo   = (const float*)d_in[3];
    const float* bo   = (const float*)d_in[4];
    float* out = (float*)d_out;

    // Workspace (110 MB):
    //  0-32  qkhi    32-64 qklo    64-80 Vt    80-96 ctxb    96-110 weights
    char* ws = (char*)d_ws;
    short* qkhi = (short*)ws;
    short* qklo = (short*)(ws + (size_t)(32u << 20));
    short* Vt   = (short*)(ws + (size_t)(64u << 20));
    short* ctxb = (short*)(ws + (size_t)(80u << 20));
    short* WhiT = (short*)(ws + (size_t)(96u << 20));
    short* WloT = (short*)(ws + (size_t)(102u << 20));
    short* WoT  = (short*)(ws + (size_t)(108u << 20));

    // 1) weight transpose+split
    transpose_split_kernel<<<dim3(48, 16), 256, 0, stream>>>(Wqkv, 3 * CEMB, WhiT, WloT);
    transpose_split_kernel<<<dim3(16, 16), 256, 0, stream>>>(Wo, CEMB, WoT, nullptr);

    // 2) qk = x @ Wqk + b  -> split hi/lo bf16, q cols pre-scaled (5 blocks/CU)
    gemm_qk_kernel<<<dim3(16, 64), 256, 0, stream>>>(
        x, WhiT, WloT, bqkv, qkhi, qklo, CEMB);

    // 3) V = x @ Wv + bv -> Vt directly (transposed epilogue)
    gemm_v_kernel<<<dim3(8, 64), 256, 0, stream>>>(
        x, WhiT + (size_t)2048 * 1024, bqkv + 2048, Vt, CEMB);

    // 4) causal MFMA flash attention -> ctx bf16 (early-K pipeline)
    attn_mfma_kernel<<<dim3(1024), 256, 0, stream>>>(qkhi, qklo, Vt, ctxb);

    // 5) out = ctx @ Wo + bo  (fp32 out, 128x64-tile counted-vmcnt pipeline)
    gemm_proj_kernel<<<dim3(16, 64), 256, 0, stream>>>(
        ctxb, WoT, bo, out, CEMB, CEMB);
}

// Round 18
// 326.852 us; speedup vs baseline: 1.4285x; 1.4285x over previous
//
#include <hip/hip_runtime.h>
#include <cstdint>
#include <cstddef>

// Problem constants: B=4, T=2048, C=1024, H=16, d=64
#define T_SEQ 2048
#define CEMB  1024
#define NHEAD 16
#define DHEAD 64

// q pre-scale: 32 (sqrt(C) quirk) * log2(e)  -> logits in log2 units
#define QSCALE 46.1662413084468f

typedef __attribute__((ext_vector_type(8))) short bf16x8;
typedef __attribute__((ext_vector_type(4))) float f32x4;

static __device__ __forceinline__ unsigned short f2bf(float x) {
    unsigned u = __builtin_bit_cast(unsigned, x);
    unsigned r = (u + 0x7FFFu + ((u >> 16) & 1u)) >> 16;
    return (unsigned short)r;
}
static __device__ __forceinline__ float bf2f(unsigned short b) {
    unsigned u = ((unsigned)b) << 16;
    return __builtin_bit_cast(float, u);
}

// async global->LDS: 16B per lane; ldsbase wave-uniform, lane offset = lane*16B.
static __device__ __forceinline__ void gload16(const short* gsrc, short* ldsbase) {
    __builtin_amdgcn_global_load_lds(
        (const __attribute__((address_space(1))) void*)gsrc,
        (__attribute__((address_space(3))) void*)ldsbase, 16, 0, 0);
}

// ---------------------------------------------------------------------------
// QK split-GEMM (R13/R16 config, known 150 us): 128x128 tile, BK=32, 256 thr.
// A = x fp32, split hi/lo in staging (VALU). B pre-split. 3 MFMAs (hh+lh+hl).
// NOTE: no min-waves launch bound — (256,5) forces VGPR<=102 < the ~108 this
// tile shape needs -> catastrophic spill (R17: WRITE_SIZE 452MB, 287us).
// Output: split hi/lo bf16, q cols (<1024) pre-scaled by QSCALE.
// LDS shorts: A_hi @0, B_hi @4096, A_lo @8192, B_lo @12288.
// ---------------------------------------------------------------------------
__global__ __launch_bounds__(256) void gemm_qk_kernel(
    const float* __restrict__ Af,
    const short* __restrict__ Bh, const short* __restrict__ Bl,
    const float* __restrict__ bias,
    short* __restrict__ Chi, short* __restrict__ Clo, int K)
{
    __shared__ __align__(16) short smem[16384];

    const int tid = threadIdx.x;
    const int w = tid >> 6, l = tid & 63;
    const int lr = l & 15, lg = l >> 4;
    const int wr = w >> 1, wc = w & 1;
    const int row0 = blockIdx.y * 128;
    const int col0 = blockIdx.x * 128;

    f32x4 acc[4][4];
    #pragma unroll
    for (int mt = 0; mt < 4; ++mt)
        #pragma unroll
        for (int nt = 0; nt < 4; ++nt)
            acc[mt][nt] = (f32x4){0.f, 0.f, 0.f, 0.f};

    const int sB0 = w * 128 + l, sB1 = sB0 + 64;
    const size_t bO0 = (size_t)(col0 + (sB0 & 127)) * K + (sB0 >> 7) * 8;
    const size_t bO1 = (size_t)(col0 + (sB1 & 127)) * K + (sB1 >> 7) * 8;
    const short* gB0  = Bh + bO0;  const short* gB1  = Bh + bO1;
    const short* gBl0 = Bl + bO0;  const short* gBl1 = Bl + bO1;
    short* const dB0 = &smem[4096 + (w * 128) * 8];
    short* const dB1 = &smem[4096 + (w * 128 + 64) * 8];

    const int arow = tid >> 1, ahalf = tid & 1;
    const float* gAf = Af + (size_t)(row0 + arow) * K + ahalf * 16;

    for (int kt = 0; kt < K; kt += 32) {
        __syncthreads();
        gload16(gB0 + kt, dB0);
        gload16(gB1 + kt, dB1);
        gload16(gBl0 + kt, dB0 + 8192);   // -> 12288 region
        gload16(gBl1 + kt, dB1 + 8192);
        {
            const float* src = gAf + kt;
            float4 f0 = *(const float4*)(src);
            float4 f1 = *(const float4*)(src + 4);
            float4 f2 = *(const float4*)(src + 8);
            float4 f3 = *(const float4*)(src + 12);
            float xs[16] = {f0.x, f0.y, f0.z, f0.w, f1.x, f1.y, f1.z, f1.w,
                            f2.x, f2.y, f2.z, f2.w, f3.x, f3.y, f3.z, f3.w};
            #pragma unroll
            for (int q = 0; q < 2; ++q) {
                bf16x8 h8, l8;
                #pragma unroll
                for (int e = 0; e < 8; ++e) {
                    float x = xs[q * 8 + e];
                    unsigned u = __builtin_bit_cast(unsigned, x);
                    h8[e] = (short)(unsigned short)(u >> 16);
                    float hf = __builtin_bit_cast(float, u & 0xFFFF0000u);
                    l8[e] = (short)f2bf(x - hf);
                }
                int slot = (ahalf * 2 + q) * 128 + arow;
                *(bf16x8*)&smem[slot * 8] = h8;
                *(bf16x8*)&smem[8192 + slot * 8] = l8;
            }
        }
        __syncthreads();

        const int ao = (lg * 128 + wr * 64 + lr) * 8;
        const int bo = 4096 + (lg * 128 + wc * 64 + lr) * 8;
        bf16x8 ahf[4], alf[4];
        #pragma unroll
        for (int mt = 0; mt < 4; ++mt) {
            ahf[mt] = *(const bf16x8*)&smem[ao + mt * 128];
            alf[mt] = *(const bf16x8*)&smem[8192 + ao + mt * 128];
        }
        #pragma unroll
        for (int nt = 0; nt < 4; ++nt) {
            bf16x8 bhf = *(const bf16x8*)&smem[bo + nt * 128];
            bf16x8 blf = *(const bf16x8*)&smem[8192 + bo + nt * 128];
            #pragma unroll
            for (int mt = 0; mt < 4; ++mt) {
                acc[mt][nt] = __builtin_amdgcn_mfma_f32_16x16x32_bf16(ahf[mt], bhf, acc[mt][nt], 0, 0, 0);
                acc[mt][nt] = __builtin_amdgcn_mfma_f32_16x16x32_bf16(alf[mt], bhf, acc[mt][nt], 0, 0, 0);
                acc[mt][nt] = __builtin_amdgcn_mfma_f32_16x16x32_bf16(ahf[mt], blf, acc[mt][nt], 0, 0, 0);
            }
        }
    }

    #pragma unroll
    for (int mt = 0; mt < 4; ++mt) {
        #pragma unroll
        for (int r = 0; r < 4; ++r) {
            int m = row0 + wr * 64 + mt * 16 + lg * 4 + r;
            #pragma unroll
            for (int nt = 0; nt < 4; ++nt) {
                int n = col0 + wc * 64 + nt * 16 + lr;
                float v = acc[mt][nt][r] + bias[n];
                if (n < 1024) v *= QSCALE;
                unsigned u = __builtin_bit_cast(unsigned, v);
                Chi[(size_t)m * 2048 + n] = (short)(unsigned short)(u >> 16);
                float hf = __builtin_bit_cast(float, u & 0xFFFF0000u);
                Clo[(size_t)m * 2048 + n] = (short)f2bf(v - hf);
            }
        }
    }
}

// ---------------------------------------------------------------------------
// V-GEMM (R13 config): A = x fp32 (RNE->bf16 in staging), B bf16; transposed
// epilogue writes Vt[B][H][64][T] directly (no repack kernel).
// ---------------------------------------------------------------------------
__global__ __launch_bounds__(256) void gemm_v_kernel(
    const float* __restrict__ Af, const short* __restrict__ Bh,
    const float* __restrict__ bias, short* __restrict__ vt, int K)
{
    __shared__ __align__(16) short smem[17408];   // staging 8192; epilogue 128*136

    const int tid = threadIdx.x;
    const int w = tid >> 6, l = tid & 63;
    const int lr = l & 15, lg = l >> 4;
    const int wr = w >> 1, wc = w & 1;
    const int row0 = blockIdx.y * 128;
    const int col0 = blockIdx.x * 128;

    f32x4 acc[4][4];
    #pragma unroll
    for (int mt = 0; mt < 4; ++mt)
        #pragma unroll
        for (int nt = 0; nt < 4; ++nt)
            acc[mt][nt] = (f32x4){0.f, 0.f, 0.f, 0.f};

    const int sB0 = w * 128 + l, sB1 = sB0 + 64;
    const size_t bO0 = (size_t)(col0 + (sB0 & 127)) * K + (sB0 >> 7) * 8;
    const size_t bO1 = (size_t)(col0 + (sB1 & 127)) * K + (sB1 >> 7) * 8;
    const short* gB0 = Bh + bO0;  const short* gB1 = Bh + bO1;
    short* const dB0 = &smem[4096 + (w * 128) * 8];
    short* const dB1 = &smem[4096 + (w * 128 + 64) * 8];

    const int arow = tid >> 1, ahalf = tid & 1;
    const float* gAf = Af + (size_t)(row0 + arow) * K + ahalf * 16;

    for (int kt = 0; kt < K; kt += 32) {
        __syncthreads();
        gload16(gB0 + kt, dB0);
        gload16(gB1 + kt, dB1);
        {
            const float* src = gAf + kt;
            float4 f0 = *(const float4*)(src);
            float4 f1 = *(const float4*)(src + 4);
            float4 f2 = *(const float4*)(src + 8);
            float4 f3 = *(const float4*)(src + 12);
            float xs[16] = {f0.x, f0.y, f0.z, f0.w, f1.x, f1.y, f1.z, f1.w,
                            f2.x, f2.y, f2.z, f2.w, f3.x, f3.y, f3.z, f3.w};
            #pragma unroll
            for (int q = 0; q < 2; ++q) {
                bf16x8 h8;
                #pragma unroll
                for (int e = 0; e < 8; ++e) h8[e] = (short)f2bf(xs[q * 8 + e]);
                int slot = (ahalf * 2 + q) * 128 + arow;
                *(bf16x8*)&smem[slot * 8] = h8;
            }
        }
        __syncthreads();

        const int ao = (lg * 128 + wr * 64 + lr) * 8;
        const int bo = 4096 + (lg * 128 + wc * 64 + lr) * 8;
        bf16x8 ahf[4];
        #pragma unroll
        for (int mt = 0; mt < 4; ++mt)
            ahf[mt] = *(const bf16x8*)&smem[ao + mt * 128];
        #pragma unroll
        for (int nt = 0; nt < 4; ++nt) {
            bf16x8 bhf = *(const bf16x8*)&smem[bo + nt * 128];
            #pragma unroll
            for (int mt = 0; mt < 4; ++mt)
                acc[mt][nt] = __builtin_amdgcn_mfma_f32_16x16x32_bf16(ahf[mt], bhf, acc[mt][nt], 0, 0, 0);
        }
    }

    // ---- transposed epilogue: acc -> smem[n_local][t_local] (pad 136) ----
    __syncthreads();
    #pragma unroll
    for (int mt = 0; mt < 4; ++mt) {
        const int tb = wr * 64 + mt * 16 + lg * 4;
        #pragma unroll
        for (int nt = 0; nt < 4; ++nt) {
            const int nl = wc * 64 + nt * 16 + lr;
            float bv = bias[col0 + nl];
            unsigned u0 = (unsigned)f2bf(acc[mt][nt][0] + bv) |
                          ((unsigned)f2bf(acc[mt][nt][1] + bv) << 16);
            unsigned u1 = (unsigned)f2bf(acc[mt][nt][2] + bv) |
                          ((unsigned)f2bf(acc[mt][nt][3] + bv) << 16);
            uint2 uu; uu.x = u0; uu.y = u1;
            *(uint2*)&smem[nl * 136 + tb] = uu;
        }
    }
    __syncthreads();

    const int b  = row0 >> 11;
    const int t0 = row0 & 2047;
    #pragma unroll
    for (int i = 0; i < 8; ++i) {
        int nl = (tid >> 4) + i * 16;
        int t8 = (tid & 15) * 8;
        bf16x8 vv = *(const bf16x8*)&smem[nl * 136 + t8];
        int n = col0 + nl;
        int hh = n >> 6, d = n & 63;
        short* dst = vt + ((size_t)((b * NHEAD + hh) * DHEAD + d)) * T_SEQ + t0 + t8;
        *(bf16x8*)dst = vv;
    }
}

// ---------------------------------------------------------------------------
// Proj GEMM with counted-vmcnt double-buffer pipeline (R13 config, 36 us).
// 128x128 tile, BK=32; stage t+1 before waiting on t; vmcnt(4) mid-loop.
// ---------------------------------------------------------------------------
__global__ __launch_bounds__(256) void gemm_proj_kernel(
    const short* __restrict__ Ah, const short* __restrict__ Bh,
    const float* __restrict__ bias, float* __restrict__ Cout, int K, int ldc)
{
    __shared__ __align__(16) short smem[16384];   // 2 buffers x 8192 shorts

    const int tid = threadIdx.x;
    const int w = tid >> 6, l = tid & 63;
    const int lr = l & 15, lg = l >> 4;
    const int wr = w >> 1, wc = w & 1;
    const int row0 = blockIdx.y * 128;
    const int col0 = blockIdx.x * 128;

    f32x4 acc[4][4];
    #pragma unroll
    for (int mt = 0; mt < 4; ++mt)
        #pragma unroll
        for (int nt = 0; nt < 4; ++nt)
            acc[mt][nt] = (f32x4){0.f, 0.f, 0.f, 0.f};

    const int s0 = w * 128 + l, s1 = s0 + 64;
    const size_t aoff0 = (size_t)(row0 + (s0 & 127)) * K + (s0 >> 7) * 8;
    const size_t aoff1 = (size_t)(row0 + (s1 & 127)) * K + (s1 >> 7) * 8;
    const size_t boff0 = (size_t)(col0 + (s0 & 127)) * K + (s0 >> 7) * 8;
    const size_t boff1 = (size_t)(col0 + (s1 & 127)) * K + (s1 >> 7) * 8;
    const short* gA0 = Ah + aoff0;  const short* gA1 = Ah + aoff1;
    const short* gB0 = Bh + boff0;  const short* gB1 = Bh + boff1;
    short* const dA0 = &smem[(w * 128) * 8];
    short* const dA1 = &smem[(w * 128 + 64) * 8];
    short* const dB0 = &smem[4096 + (w * 128) * 8];
    short* const dB1 = &smem[4096 + (w * 128 + 64) * 8];

    #define PSTAGE(buf, kt) do {                      \
        gload16(gA0 + (kt), dA0 + (buf) * 8192);      \
        gload16(gA1 + (kt), dA1 + (buf) * 8192);      \
        gload16(gB0 + (kt), dB0 + (buf) * 8192);      \
        gload16(gB1 + (kt), dB1 + (buf) * 8192);      \
    } while (0)

    const int nkt = K / 32;
    PSTAGE(0, 0);
    for (int ti = 0; ti < nkt; ++ti) {
        if (ti + 1 < nkt) {
            PSTAGE((ti + 1) & 1, (ti + 1) * 32);
            asm volatile("s_waitcnt vmcnt(4)" ::: "memory");
        } else {
            asm volatile("s_waitcnt vmcnt(0)" ::: "memory");
        }
        __builtin_amdgcn_s_barrier();
        __builtin_amdgcn_sched_barrier(0);

        const int sb = (ti & 1) * 8192;
        const int ao = sb + (lg * 128 + wr * 64 + lr) * 8;
        const int bo = sb + 4096 + (lg * 128 + wc * 64 + lr) * 8;
        bf16x8 ahf[4];
        #pragma unroll
        for (int mt = 0; mt < 4; ++mt)
            ahf[mt] = *(const bf16x8*)&smem[ao + mt * 128];
        #pragma unroll
        for (int nt = 0; nt < 4; ++nt) {
            bf16x8 bhf = *(const bf16x8*)&smem[bo + nt * 128];
            #pragma unroll
            for (int mt = 0; mt < 4; ++mt)
                acc[mt][nt] = __builtin_amdgcn_mfma_f32_16x16x32_bf16(ahf[mt], bhf, acc[mt][nt], 0, 0, 0);
        }
        __builtin_amdgcn_sched_barrier(0);
        __builtin_amdgcn_s_barrier();
        __builtin_amdgcn_sched_barrier(0);
    }
    #undef PSTAGE

    #pragma unroll
    for (int mt = 0; mt < 4; ++mt) {
        #pragma unroll
        for (int r = 0; r < 4; ++r) {
            int m = row0 + wr * 64 + mt * 16 + lg * 4 + r;
            #pragma unroll
            for (int nt = 0; nt < 4; ++nt) {
                int n = col0 + wc * 64 + nt * 16 + lr;
                Cout[(size_t)m * ldc + n] = acc[mt][nt][r] + bias[n];
            }
        }
    }
}

// ---------------------------------------------------------------------------
// Transpose + hi/lo bf16 split: src fp32 [Krows][nsrc] -> hi/lo [N][1024]
// ---------------------------------------------------------------------------
__global__ __launch_bounds__(256) void transpose_split_kernel(
    const float* __restrict__ src, int nsrc,
    short* __restrict__ hi, short* __restrict__ lo)
{
    __shared__ float tile[64][68];
    const int tid = threadIdx.x;
    const int n0 = blockIdx.x * 64, k0 = blockIdx.y * 64;
    {
        int kr = tid >> 2, cg = tid & 3;
        const float* s = src + (size_t)(k0 + kr) * nsrc + n0 + cg * 16;
        #pragma unroll
        for (int q = 0; q < 4; ++q) {
            float4 f = *(const float4*)(s + q * 4);
            tile[kr][cg * 16 + q * 4 + 0] = f.x;
            tile[kr][cg * 16 + q * 4 + 1] = f.y;
            tile[kr][cg * 16 + q * 4 + 2] = f.z;
            tile[kr][cg * 16 + q * 4 + 3] = f.w;
        }
    }
    __syncthreads();
    {
        int nr = tid >> 2, kg = tid & 3;
        int n = n0 + nr;
        bf16x8 h0, h1, lo0, lo1;
        #pragma unroll
        for (int e = 0; e < 8; ++e) {
            float a = tile[kg * 16 + e][nr];
            float b = tile[kg * 16 + 8 + e][nr];
            unsigned short ha = f2bf(a), hb = f2bf(b);
            h0[e] = (short)ha; h1[e] = (short)hb;
            lo0[e] = (short)f2bf(a - bf2f(ha));
            lo1[e] = (short)f2bf(b - bf2f(hb));
        }
        short* dh = hi + (size_t)n * 1024 + k0 + kg * 16;
        *(bf16x8*)dh = h0;
        *(bf16x8*)(dh + 8) = h1;
        if (lo) {
            short* dl = lo + (size_t)n * 1024 + k0 + kg * 16;
            *(bf16x8*)dl = lo0;
            *(bf16x8*)(dl + 8) = lo1;
        }
    }
}

// ---------------------------------------------------------------------------
// MFMA flash attention (causal), swapped QK^T + counted-vmcnt V-dbuf pipeline
// + early-K issue (R15/R16-validated, ~79 us).
// ---------------------------------------------------------------------------
__global__ __launch_bounds__(256) void attn_mfma_kernel(
    const short* __restrict__ qkhi, const short* __restrict__ qklo,
    const short* __restrict__ vt, short* __restrict__ ctxb)
{
    __shared__ __align__(16) short smem[20480];   // 40960 B

    const int tid = threadIdx.x;
    const int w = tid >> 6, l = tid & 63;
    const int lr = l & 15, lg = l >> 4;

    const int bid = blockIdx.x;
    const int p  = bid >> 6;
    const int bh = bid & 63;
    const int h = bh & 15, b = bh >> 4;
    const size_t bT = (size_t)b * T_SEQ;

    const int g0 = w * 128 + l, g1 = g0 + 64;
    const int rg0 = g0 >> 3, rg1 = g1 >> 3;
    const int sc0 = (g0 & 7) ^ (rg0 & 7), sc1 = (g1 & 7) ^ (rg1 & 7);
    short* const dK0 = &smem[(w * 128) * 8];
    short* const dK1 = &smem[(w * 128 + 64) * 8];

    const size_t koff0 = (bT + rg0) * 2048 + 1024 + h * DHEAD + sc0 * 8;
    const size_t koff1 = (bT + rg1) * 2048 + 1024 + h * DHEAD + sc1 * 8;
    const short* const pKh0 = qkhi + koff0;
    const short* const pKh1 = qkhi + koff1;
    const short* const pKl0 = qklo + koff0;
    const short* const pKl1 = qklo + koff1;
    const short* const pV0 = vt + ((size_t)((b * NHEAD + h) * DHEAD) + rg0) * T_SEQ + sc0 * 8;
    const short* const pV1 = vt + ((size_t)((b * NHEAD + h) * DHEAD) + rg1) * T_SEQ + sc1 * 8;

    const int psBase = 16384 + w * 1024;
    const int pwChunk = (lg >> 1);
    const int pwIntra = (lg & 1) * 4;

    for (int half = 0; half < 2; ++half) {
        const int xi = half ? (31 - p) : p;
        const int qw = xi * 64 + w * 16;
        const int nsteps = xi + 1;

        __syncthreads();

        bf16x8 qhi[2], qlo[2];
        #pragma unroll
        for (int kk = 0; kk < 2; ++kk) {
            size_t off = (bT + qw + lr) * 2048 + h * DHEAD + kk * 32 + lg * 8;
            qhi[kk] = *(const bf16x8*)(qkhi + off);
            qlo[kk] = *(const bf16x8*)(qklo + off);
        }
        __builtin_amdgcn_sched_barrier(0);

        gload16(pKh0, dK0);
        gload16(pKh1, dK1);
        gload16(pKl0, dK0 + 4096);
        gload16(pKl1, dK1 + 4096);
        gload16(pV0, dK0 + 8192);
        gload16(pV1, dK1 + 8192);
        {
            int j1 = (nsteps > 1) ? 64 : 0;
            gload16(pV0 + j1, dK0 + 12288);
            gload16(pV1 + j1, dK1 + 12288);
        }

        f32x4 O[4];
        #pragma unroll
        for (int dt = 0; dt < 4; ++dt)
            O[dt] = (f32x4){0.f, 0.f, 0.f, 0.f};
        float mrow = -3.0e38f;
        float lrow = 0.f;

        for (int t = 0; t < nsteps; ++t) {
            const int j0 = t * 64;
            asm volatile("s_waitcnt vmcnt(2)" ::: "memory");
            __builtin_amdgcn_s_barrier();
            __builtin_amdgcn_sched_barrier(0);
            const int vbase = 8192 + (t & 1) * 4096;

            f32x4 St[4];
            __builtin_amdgcn_s_setprio(1);
            #pragma unroll
            for (int ct = 0; ct < 4; ++ct) {
                f32x4 s = (f32x4){0.f, 0.f, 0.f, 0.f};
                #pragma unroll
                for (int kk = 0; kk < 2; ++kk) {
                    int j  = ct * 16 + lr;
                    int ck = kk * 4 + lg;
                    int idx = j * 64 + ((ck ^ (j & 7)) << 3);
                    bf16x8 kh8 = *(bf16x8*)&smem[idx];
                    bf16x8 kl8 = *(bf16x8*)&smem[4096 + idx];
                    s = __builtin_amdgcn_mfma_f32_16x16x32_bf16(kh8, qhi[kk], s, 0, 0, 0);
                    s = __builtin_amdgcn_mfma_f32_16x16x32_bf16(kh8, qlo[kk], s, 0, 0, 0);
                    s = __builtin_amdgcn_mfma_f32_16x16x32_bf16(kl8, qhi[kk], s, 0, 0, 0);
                }
                St[ct] = s;
            }
            __builtin_amdgcn_s_setprio(0);
            __builtin_amdgcn_sched_barrier(0);
            __builtin_amdgcn_s_barrier();      // all waves' K ds_reads complete
            __builtin_amdgcn_sched_barrier(0);
            if (t + 1 < nsteps) {              // early K(t+1): flies under SM+PV
                size_t ko = (size_t)(t + 1) * 131072;
                gload16(pKh0 + ko, dK0);
                gload16(pKh1 + ko, dK1);
                gload16(pKl0 + ko, dK0 + 4096);
                gload16(pKl1 + ko, dK1 + 4096);
            }

            #pragma unroll
            for (int ct = 0; ct < 4; ++ct) {
                if (j0 + ct * 16 + 15 > qw) {
                    #pragma unroll
                    for (int r = 0; r < 4; ++r) {
                        int jabs = j0 + ct * 16 + lg * 4 + r;
                        St[ct][r] = (jabs <= qw + lr) ? St[ct][r] : -3.0e38f;
                    }
                }
            }

            float tm = fmaxf(fmaxf(fmaxf(St[0][0], St[0][1]), fmaxf(St[0][2], St[0][3])),
                             fmaxf(fmaxf(St[1][0], St[1][1]), fmaxf(St[1][2], St[1][3])));
            tm = fmaxf(tm, fmaxf(fmaxf(fmaxf(St[2][0], St[2][1]), fmaxf(St[2][2], St[2][3])),
                                 fmaxf(fmaxf(St[3][0], St[3][1]), fmaxf(St[3][2], St[3][3]))));
            tm = fmaxf(tm, __shfl_xor(tm, 16));
            tm = fmaxf(tm, __shfl_xor(tm, 32));

            if (__any(tm > mrow)) {
                float mnew  = fmaxf(mrow, tm);
                float alpha = __builtin_amdgcn_exp2f(mrow - mnew);
                mrow = mnew;
                lrow *= alpha;
                #pragma unroll
                for (int r = 0; r < 4; ++r) {
                    float aO = __shfl(alpha, lg * 4 + r);
                    #pragma unroll
                    for (int dt = 0; dt < 4; ++dt)
                        O[dt][r] *= aO;
                }
            }

            #pragma unroll
            for (int ct = 0; ct < 4; ++ct) {
                float p0 = __builtin_amdgcn_exp2f(St[ct][0] - mrow);
                float p1 = __builtin_amdgcn_exp2f(St[ct][1] - mrow);
                float p2 = __builtin_amdgcn_exp2f(St[ct][2] - mrow);
                float p3 = __builtin_amdgcn_exp2f(St[ct][3] - mrow);
                lrow += (p0 + p1) + (p2 + p3);
                unsigned u0 = (__builtin_bit_cast(unsigned, p0) >> 16) |
                              (__builtin_bit_cast(unsigned, p1) & 0xFFFF0000u);
                unsigned u1 = (__builtin_bit_cast(unsigned, p2) >> 16) |
                              (__builtin_bit_cast(unsigned, p3) & 0xFFFF0000u);
                int chunk = ct * 2 + pwChunk;
                int sidx = psBase + lr * 64 + ((chunk ^ (lr & 7)) << 3) + pwIntra;
                uint2 uu; uu.x = u0; uu.y = u1;
                *(uint2*)&smem[sidx] = uu;
            }

            __builtin_amdgcn_wave_barrier();

            bf16x8 pa[2];
            #pragma unroll
            for (int jk = 0; jk < 2; ++jk) {
                int ck = jk * 4 + lg;
                pa[jk] = *(bf16x8*)&smem[psBase + lr * 64 + ((ck ^ (lr & 7)) << 3)];
            }
            __builtin_amdgcn_s_setprio(1);
            #pragma unroll
            for (int dt = 0; dt < 4; ++dt) {
                #pragma unroll
                for (int jk = 0; jk < 2; ++jk) {
                    int d  = dt * 16 + lr;
                    int ck = jk * 4 + lg;
                    bf16x8 vb = *(bf16x8*)&smem[vbase + d * 64 + ((ck ^ (d & 7)) << 3)];
                    O[dt] = __builtin_amdgcn_mfma_f32_16x16x32_bf16(pa[jk], vb, O[dt], 0, 0, 0);
                }
            }
            __builtin_amdgcn_s_setprio(0);

            __builtin_amdgcn_sched_barrier(0);
            __builtin_amdgcn_s_barrier();      // all PV reads of V(t) done
            __builtin_amdgcn_sched_barrier(0);

            if (t + 1 < nsteps) {              // V(t+2) into buf (t&1)
                int jv = (t + 2 < nsteps) ? (t + 2) : (nsteps - 1);
                short* const dV = &smem[8192 + (t & 1) * 4096];
                gload16(pV0 + jv * 64, dV + (w * 128) * 8);
                gload16(pV1 + jv * 64, dV + (w * 128 + 64) * 8);
            }
        }

        float lsum = lrow + __shfl_xor(lrow, 16);
        lsum += __shfl_xor(lsum, 32);
        #pragma unroll
        for (int r = 0; r < 4; ++r) {
            float lO = __shfl(lsum, lg * 4 + r);
            float inv = 1.0f / lO;
            int row = qw + lg * 4 + r;
            #pragma unroll
            for (int dt = 0; dt < 4; ++dt) {
                int col = h * DHEAD + dt * 16 + lr;
                ctxb[(size_t)(b * T_SEQ + row) * CEMB + col] = (short)f2bf(O[dt][r] * inv);
            }
        }
    }
}

// ---------------------------------------------------------------------------
extern "C" void kernel_launch(void* const* d_in, const int* in_sizes, int n_in,
                              void* d_out, int out_size, void* d_ws, size_t ws_size,
                              hipStream_t stream)
{
    const float* x    = (const float*)d_in[0];
    const float* Wqkv = (const float*)d_in[1];
    const float* bqkv = (const float*)d_in[2];
    const float* Wo   = (const float*)d_in[3];
    const float* bo   = (const float*)d_in[4];
    float* out = (float*)d_out;

    // Workspace (110 MB):
    //  0-32  qkhi    32-64 qklo    64-80 Vt    80-96 ctxb    96-110 weights
    char* ws = (char*)d_ws;
    short* qkhi = (short*)ws;
    short* qklo = (short*)(ws + (size_t)(32u << 20));
    short* Vt   = (short*)(ws + (size_t)(64u << 20));
    short* ctxb = (short*)(ws + (size_t)(80u << 20));
    short* WhiT = (short*)(ws + (size_t)(96u << 20));
    short* WloT = (short*)(ws + (size_t)(102u << 20));
    short* WoT  = (short*)(ws + (size_t)(108u << 20));

    // 1) weight transpose+split
    transpose_split_kernel<<<dim3(48, 16), 256, 0, stream>>>(Wqkv, 3 * CEMB, WhiT, WloT);
    transpose_split_kernel<<<dim3(16, 16), 256, 0, stream>>>(Wo, CEMB, WoT, nullptr);

    // 2) qk = x @ Wqk + b  -> split hi/lo bf16, q cols pre-scaled
    gemm_qk_kernel<<<dim3(16, 64), 256, 0, stream>>>(
        x, WhiT, WloT, bqkv, qkhi, qklo, CEMB);

    // 3) V = x @ Wv + bv -> Vt directly (transposed epilogue)
    gemm_v_kernel<<<dim3(8, 64), 256, 0, stream>>>(
        x, WhiT + (size_t)2048 * 1024, bqkv + 2048, Vt, CEMB);

    // 4) causal MFMA flash attention -> ctx bf16 (early-K pipeline)
    attn_mfma_kernel<<<dim3(1024), 256, 0, stream>>>(qkhi, qklo, Vt, ctxb);

    // 5) out = ctx @ Wo + bo  (fp32 out, counted-vmcnt pipeline)
    gemm_proj_kernel<<<dim3(8, 64), 256, 0, stream>>>(
        ctxb, WoT, bo, out, CEMB, CEMB);
}

// Round 19
// 321.433 us; speedup vs baseline: 1.4526x; 1.0169x over previous
//
#include <hip/hip_runtime.h>
#include <cstdint>
#include <cstddef>

// Problem constants: B=4, T=2048, C=1024, H=16, d=64
#define T_SEQ 2048
#define CEMB  1024
#define NHEAD 16
#define DHEAD 64

// q pre-scale: 32 (sqrt(C) quirk) * log2(e)  -> logits in log2 units
#define QSCALE 46.1662413084468f

typedef __attribute__((ext_vector_type(8))) short bf16x8;
typedef __attribute__((ext_vector_type(4))) float f32x4;

static __device__ __forceinline__ unsigned short f2bf(float x) {
    unsigned u = __builtin_bit_cast(unsigned, x);
    unsigned r = (u + 0x7FFFu + ((u >> 16) & 1u)) >> 16;
    return (unsigned short)r;
}
static __device__ __forceinline__ float bf2f(unsigned short b) {
    unsigned u = ((unsigned)b) << 16;
    return __builtin_bit_cast(float, u);
}

// async global->LDS: 16B per lane; ldsbase wave-uniform, lane offset = lane*16B.
static __device__ __forceinline__ void gload16(const short* gsrc, short* ldsbase) {
    __builtin_amdgcn_global_load_lds(
        (const __attribute__((address_space(1))) void*)gsrc,
        (__attribute__((address_space(3))) void*)ldsbase, 16, 0, 0);
}

// ---------------------------------------------------------------------------
// QK split-GEMM (R13/R16 config): 128x128 tile, BK=32, 256 threads.
// A = x fp32, split hi/lo in staging (VALU). B pre-split. 3 MFMAs (hh+lh+hl).
// R19: bijective XCD swizzle — hw bid round-robins XCDs, so logical =
// (hw&7)*128 + hw>>3 gives each XCD 8 contiguous row-tiles x 16 col-tiles
// (A footprint 4MB = one XCD L2) -> staging-drain waits hit L2 not L3/HBM.
// LDS shorts: A_hi @0, B_hi @4096, A_lo @8192, B_lo @12288.
// ---------------------------------------------------------------------------
__global__ __launch_bounds__(256) void gemm_qk_kernel(
    const float* __restrict__ Af,
    const short* __restrict__ Bh, const short* __restrict__ Bl,
    const float* __restrict__ bias,
    short* __restrict__ Chi, short* __restrict__ Clo, int K)
{
    __shared__ __align__(16) short smem[16384];

    const int tid = threadIdx.x;
    const int w = tid >> 6, l = tid & 63;
    const int lr = l & 15, lg = l >> 4;
    const int wr = w >> 1, wc = w & 1;
    const int hw = blockIdx.x;                     // 0..1023
    const int logical = (hw & 7) * 128 + (hw >> 3);
    const int row0 = (logical >> 4) * 128;         // 64 row-tiles
    const int col0 = (logical & 15) * 128;         // 16 col-tiles

    f32x4 acc[4][4];
    #pragma unroll
    for (int mt = 0; mt < 4; ++mt)
        #pragma unroll
        for (int nt = 0; nt < 4; ++nt)
            acc[mt][nt] = (f32x4){0.f, 0.f, 0.f, 0.f};

    const int sB0 = w * 128 + l, sB1 = sB0 + 64;
    const size_t bO0 = (size_t)(col0 + (sB0 & 127)) * K + (sB0 >> 7) * 8;
    const size_t bO1 = (size_t)(col0 + (sB1 & 127)) * K + (sB1 >> 7) * 8;
    const short* gB0  = Bh + bO0;  const short* gB1  = Bh + bO1;
    const short* gBl0 = Bl + bO0;  const short* gBl1 = Bl + bO1;
    short* const dB0 = &smem[4096 + (w * 128) * 8];
    short* const dB1 = &smem[4096 + (w * 128 + 64) * 8];

    const int arow = tid >> 1, ahalf = tid & 1;
    const float* gAf = Af + (size_t)(row0 + arow) * K + ahalf * 16;

    for (int kt = 0; kt < K; kt += 32) {
        __syncthreads();
        gload16(gB0 + kt, dB0);
        gload16(gB1 + kt, dB1);
        gload16(gBl0 + kt, dB0 + 8192);   // -> 12288 region
        gload16(gBl1 + kt, dB1 + 8192);
        {
            const float* src = gAf + kt;
            float4 f0 = *(const float4*)(src);
            float4 f1 = *(const float4*)(src + 4);
            float4 f2 = *(const float4*)(src + 8);
            float4 f3 = *(const float4*)(src + 12);
            float xs[16] = {f0.x, f0.y, f0.z, f0.w, f1.x, f1.y, f1.z, f1.w,
                            f2.x, f2.y, f2.z, f2.w, f3.x, f3.y, f3.z, f3.w};
            #pragma unroll
            for (int q = 0; q < 2; ++q) {
                bf16x8 h8, l8;
                #pragma unroll
                for (int e = 0; e < 8; ++e) {
                    float x = xs[q * 8 + e];
                    unsigned u = __builtin_bit_cast(unsigned, x);
                    h8[e] = (short)(unsigned short)(u >> 16);
                    float hf = __builtin_bit_cast(float, u & 0xFFFF0000u);
                    l8[e] = (short)f2bf(x - hf);
                }
                int slot = (ahalf * 2 + q) * 128 + arow;
                *(bf16x8*)&smem[slot * 8] = h8;
                *(bf16x8*)&smem[8192 + slot * 8] = l8;
            }
        }
        __syncthreads();

        const int ao = (lg * 128 + wr * 64 + lr) * 8;
        const int bo = 4096 + (lg * 128 + wc * 64 + lr) * 8;
        bf16x8 ahf[4], alf[4];
        #pragma unroll
        for (int mt = 0; mt < 4; ++mt) {
            ahf[mt] = *(const bf16x8*)&smem[ao + mt * 128];
            alf[mt] = *(const bf16x8*)&smem[8192 + ao + mt * 128];
        }
        #pragma unroll
        for (int nt = 0; nt < 4; ++nt) {
            bf16x8 bhf = *(const bf16x8*)&smem[bo + nt * 128];
            bf16x8 blf = *(const bf16x8*)&smem[8192 + bo + nt * 128];
            #pragma unroll
            for (int mt = 0; mt < 4; ++mt) {
                acc[mt][nt] = __builtin_amdgcn_mfma_f32_16x16x32_bf16(ahf[mt], bhf, acc[mt][nt], 0, 0, 0);
                acc[mt][nt] = __builtin_amdgcn_mfma_f32_16x16x32_bf16(alf[mt], bhf, acc[mt][nt], 0, 0, 0);
                acc[mt][nt] = __builtin_amdgcn_mfma_f32_16x16x32_bf16(ahf[mt], blf, acc[mt][nt], 0, 0, 0);
            }
        }
    }

    #pragma unroll
    for (int mt = 0; mt < 4; ++mt) {
        #pragma unroll
        for (int r = 0; r < 4; ++r) {
            int m = row0 + wr * 64 + mt * 16 + lg * 4 + r;
            #pragma unroll
            for (int nt = 0; nt < 4; ++nt) {
                int n = col0 + wc * 64 + nt * 16 + lr;
                float v = acc[mt][nt][r] + bias[n];
                if (n < 1024) v *= QSCALE;
                unsigned u = __builtin_bit_cast(unsigned, v);
                Chi[(size_t)m * 2048 + n] = (short)(unsigned short)(u >> 16);
                float hf = __builtin_bit_cast(float, u & 0xFFFF0000u);
                Clo[(size_t)m * 2048 + n] = (short)f2bf(v - hf);
            }
        }
    }
}

// ---------------------------------------------------------------------------
// V-GEMM (R13 config + R19 XCD swizzle): A = x fp32 (RNE->bf16 in staging),
// B bf16; transposed epilogue writes Vt[B][H][64][T] directly.
// ---------------------------------------------------------------------------
__global__ __launch_bounds__(256) void gemm_v_kernel(
    const float* __restrict__ Af, const short* __restrict__ Bh,
    const float* __restrict__ bias, short* __restrict__ vt, int K)
{
    __shared__ __align__(16) short smem[17408];   // staging 8192; epilogue 128*136

    const int tid = threadIdx.x;
    const int w = tid >> 6, l = tid & 63;
    const int lr = l & 15, lg = l >> 4;
    const int wr = w >> 1, wc = w & 1;
    const int hw = blockIdx.x;                    // 0..511
    const int logical = (hw & 7) * 64 + (hw >> 3);
    const int row0 = (logical >> 3) * 128;        // 64 row-tiles
    const int col0 = (logical & 7) * 128;         // 8 col-tiles

    f32x4 acc[4][4];
    #pragma unroll
    for (int mt = 0; mt < 4; ++mt)
        #pragma unroll
        for (int nt = 0; nt < 4; ++nt)
            acc[mt][nt] = (f32x4){0.f, 0.f, 0.f, 0.f};

    const int sB0 = w * 128 + l, sB1 = sB0 + 64;
    const size_t bO0 = (size_t)(col0 + (sB0 & 127)) * K + (sB0 >> 7) * 8;
    const size_t bO1 = (size_t)(col0 + (sB1 & 127)) * K + (sB1 >> 7) * 8;
    const short* gB0 = Bh + bO0;  const short* gB1 = Bh + bO1;
    short* const dB0 = &smem[4096 + (w * 128) * 8];
    short* const dB1 = &smem[4096 + (w * 128 + 64) * 8];

    const int arow = tid >> 1, ahalf = tid & 1;
    const float* gAf = Af + (size_t)(row0 + arow) * K + ahalf * 16;

    for (int kt = 0; kt < K; kt += 32) {
        __syncthreads();
        gload16(gB0 + kt, dB0);
        gload16(gB1 + kt, dB1);
        {
            const float* src = gAf + kt;
            float4 f0 = *(const float4*)(src);
            float4 f1 = *(const float4*)(src + 4);
            float4 f2 = *(const float4*)(src + 8);
            float4 f3 = *(const float4*)(src + 12);
            float xs[16] = {f0.x, f0.y, f0.z, f0.w, f1.x, f1.y, f1.z, f1.w,
                            f2.x, f2.y, f2.z, f2.w, f3.x, f3.y, f3.z, f3.w};
            #pragma unroll
            for (int q = 0; q < 2; ++q) {
                bf16x8 h8;
                #pragma unroll
                for (int e = 0; e < 8; ++e) h8[e] = (short)f2bf(xs[q * 8 + e]);
                int slot = (ahalf * 2 + q) * 128 + arow;
                *(bf16x8*)&smem[slot * 8] = h8;
            }
        }
        __syncthreads();

        const int ao = (lg * 128 + wr * 64 + lr) * 8;
        const int bo = 4096 + (lg * 128 + wc * 64 + lr) * 8;
        bf16x8 ahf[4];
        #pragma unroll
        for (int mt = 0; mt < 4; ++mt)
            ahf[mt] = *(const bf16x8*)&smem[ao + mt * 128];
        #pragma unroll
        for (int nt = 0; nt < 4; ++nt) {
            bf16x8 bhf = *(const bf16x8*)&smem[bo + nt * 128];
            #pragma unroll
            for (int mt = 0; mt < 4; ++mt)
                acc[mt][nt] = __builtin_amdgcn_mfma_f32_16x16x32_bf16(ahf[mt], bhf, acc[mt][nt], 0, 0, 0);
        }
    }

    // ---- transposed epilogue: acc -> smem[n_local][t_local] (pad 136) ----
    __syncthreads();
    #pragma unroll
    for (int mt = 0; mt < 4; ++mt) {
        const int tb = wr * 64 + mt * 16 + lg * 4;
        #pragma unroll
        for (int nt = 0; nt < 4; ++nt) {
            const int nl = wc * 64 + nt * 16 + lr;
            float bv = bias[col0 + nl];
            unsigned u0 = (unsigned)f2bf(acc[mt][nt][0] + bv) |
                          ((unsigned)f2bf(acc[mt][nt][1] + bv) << 16);
            unsigned u1 = (unsigned)f2bf(acc[mt][nt][2] + bv) |
                          ((unsigned)f2bf(acc[mt][nt][3] + bv) << 16);
            uint2 uu; uu.x = u0; uu.y = u1;
            *(uint2*)&smem[nl * 136 + tb] = uu;
        }
    }
    __syncthreads();

    const int b  = row0 >> 11;
    const int t0 = row0 & 2047;
    #pragma unroll
    for (int i = 0; i < 8; ++i) {
        int nl = (tid >> 4) + i * 16;
        int t8 = (tid & 15) * 8;
        bf16x8 vv = *(const bf16x8*)&smem[nl * 136 + t8];
        int n = col0 + nl;
        int hh = n >> 6, d = n & 63;
        short* dst = vt + ((size_t)((b * NHEAD + hh) * DHEAD + d)) * T_SEQ + t0 + t8;
        *(bf16x8*)dst = vv;
    }
}

// ---------------------------------------------------------------------------
// Proj GEMM with counted-vmcnt double-buffer pipeline (R13 config, 36 us).
// ---------------------------------------------------------------------------
__global__ __launch_bounds__(256) void gemm_proj_kernel(
    const short* __restrict__ Ah, const short* __restrict__ Bh,
    const float* __restrict__ bias, float* __restrict__ Cout, int K, int ldc)
{
    __shared__ __align__(16) short smem[16384];   // 2 buffers x 8192 shorts

    const int tid = threadIdx.x;
    const int w = tid >> 6, l = tid & 63;
    const int lr = l & 15, lg = l >> 4;
    const int wr = w >> 1, wc = w & 1;
    const int row0 = blockIdx.y * 128;
    const int col0 = blockIdx.x * 128;

    f32x4 acc[4][4];
    #pragma unroll
    for (int mt = 0; mt < 4; ++mt)
        #pragma unroll
        for (int nt = 0; nt < 4; ++nt)
            acc[mt][nt] = (f32x4){0.f, 0.f, 0.f, 0.f};

    const int s0 = w * 128 + l, s1 = s0 + 64;
    const size_t aoff0 = (size_t)(row0 + (s0 & 127)) * K + (s0 >> 7) * 8;
    const size_t aoff1 = (size_t)(row0 + (s1 & 127)) * K + (s1 >> 7) * 8;
    const size_t boff0 = (size_t)(col0 + (s0 & 127)) * K + (s0 >> 7) * 8;
    const size_t boff1 = (size_t)(col0 + (s1 & 127)) * K + (s1 >> 7) * 8;
    const short* gA0 = Ah + aoff0;  const short* gA1 = Ah + aoff1;
    const short* gB0 = Bh + boff0;  const short* gB1 = Bh + boff1;
    short* const dA0 = &smem[(w * 128) * 8];
    short* const dA1 = &smem[(w * 128 + 64) * 8];
    short* const dB0 = &smem[4096 + (w * 128) * 8];
    short* const dB1 = &smem[4096 + (w * 128 + 64) * 8];

    #define PSTAGE(buf, kt) do {                      \
        gload16(gA0 + (kt), dA0 + (buf) * 8192);      \
        gload16(gA1 + (kt), dA1 + (buf) * 8192);      \
        gload16(gB0 + (kt), dB0 + (buf) * 8192);      \
        gload16(gB1 + (kt), dB1 + (buf) * 8192);      \
    } while (0)

    const int nkt = K / 32;
    PSTAGE(0, 0);
    for (int ti = 0; ti < nkt; ++ti) {
        if (ti + 1 < nkt) {
            PSTAGE((ti + 1) & 1, (ti + 1) * 32);
            asm volatile("s_waitcnt vmcnt(4)" ::: "memory");
        } else {
            asm volatile("s_waitcnt vmcnt(0)" ::: "memory");
        }
        __builtin_amdgcn_s_barrier();
        __builtin_amdgcn_sched_barrier(0);

        const int sb = (ti & 1) * 8192;
        const int ao = sb + (lg * 128 + wr * 64 + lr) * 8;
        const int bo = sb + 4096 + (lg * 128 + wc * 64 + lr) * 8;
        bf16x8 ahf[4];
        #pragma unroll
        for (int mt = 0; mt < 4; ++mt)
            ahf[mt] = *(const bf16x8*)&smem[ao + mt * 128];
        #pragma unroll
        for (int nt = 0; nt < 4; ++nt) {
            bf16x8 bhf = *(const bf16x8*)&smem[bo + nt * 128];
            #pragma unroll
            for (int mt = 0; mt < 4; ++mt)
                acc[mt][nt] = __builtin_amdgcn_mfma_f32_16x16x32_bf16(ahf[mt], bhf, acc[mt][nt], 0, 0, 0);
        }
        __builtin_amdgcn_sched_barrier(0);
        __builtin_amdgcn_s_barrier();
        __builtin_amdgcn_sched_barrier(0);
    }
    #undef PSTAGE

    #pragma unroll
    for (int mt = 0; mt < 4; ++mt) {
        #pragma unroll
        for (int r = 0; r < 4; ++r) {
            int m = row0 + wr * 64 + mt * 16 + lg * 4 + r;
            #pragma unroll
            for (int nt = 0; nt < 4; ++nt) {
                int n = col0 + wc * 64 + nt * 16 + lr;
                Cout[(size_t)m * ldc + n] = acc[mt][nt][r] + bias[n];
            }
        }
    }
}

// ---------------------------------------------------------------------------
// Transpose + hi/lo bf16 split: src fp32 [Krows][nsrc] -> hi/lo [N][1024]
// ---------------------------------------------------------------------------
__global__ __launch_bounds__(256) void transpose_split_kernel(
    const float* __restrict__ src, int nsrc,
    short* __restrict__ hi, short* __restrict__ lo)
{
    __shared__ float tile[64][68];
    const int tid = threadIdx.x;
    const int n0 = blockIdx.x * 64, k0 = blockIdx.y * 64;
    {
        int kr = tid >> 2, cg = tid & 3;
        const float* s = src + (size_t)(k0 + kr) * nsrc + n0 + cg * 16;
        #pragma unroll
        for (int q = 0; q < 4; ++q) {
            float4 f = *(const float4*)(s + q * 4);
            tile[kr][cg * 16 + q * 4 + 0] = f.x;
            tile[kr][cg * 16 + q * 4 + 1] = f.y;
            tile[kr][cg * 16 + q * 4 + 2] = f.z;
            tile[kr][cg * 16 + q * 4 + 3] = f.w;
        }
    }
    __syncthreads();
    {
        int nr = tid >> 2, kg = tid & 3;
        int n = n0 + nr;
        bf16x8 h0, h1, lo0, lo1;
        #pragma unroll
        for (int e = 0; e < 8; ++e) {
            float a = tile[kg * 16 + e][nr];
            float b = tile[kg * 16 + 8 + e][nr];
            unsigned short ha = f2bf(a), hb = f2bf(b);
            h0[e] = (short)ha; h1[e] = (short)hb;
            lo0[e] = (short)f2bf(a - bf2f(ha));
            lo1[e] = (short)f2bf(b - bf2f(hb));
        }
        short* dh = hi + (size_t)n * 1024 + k0 + kg * 16;
        *(bf16x8*)dh = h0;
        *(bf16x8*)(dh + 8) = h1;
        if (lo) {
            short* dl = lo + (size_t)n * 1024 + k0 + kg * 16;
            *(bf16x8*)dl = lo0;
            *(bf16x8*)(dl + 8) = lo1;
        }
    }
}

// ---------------------------------------------------------------------------
// MFMA flash attention (causal), swapped QK^T + counted-vmcnt V-dbuf pipeline
// + early-K issue (R15/R16-validated, ~79 us). Unchanged.
// ---------------------------------------------------------------------------
__global__ __launch_bounds__(256) void attn_mfma_kernel(
    const short* __restrict__ qkhi, const short* __restrict__ qklo,
    const short* __restrict__ vt, short* __restrict__ ctxb)
{
    __shared__ __align__(16) short smem[20480];   // 40960 B

    const int tid = threadIdx.x;
    const int w = tid >> 6, l = tid & 63;
    const int lr = l & 15, lg = l >> 4;

    const int bid = blockIdx.x;
    const int p  = bid >> 6;
    const int bh = bid & 63;
    const int h = bh & 15, b = bh >> 4;
    const size_t bT = (size_t)b * T_SEQ;

    const int g0 = w * 128 + l, g1 = g0 + 64;
    const int rg0 = g0 >> 3, rg1 = g1 >> 3;
    const int sc0 = (g0 & 7) ^ (rg0 & 7), sc1 = (g1 & 7) ^ (rg1 & 7);
    short* const dK0 = &smem[(w * 128) * 8];
    short* const dK1 = &smem[(w * 128 + 64) * 8];

    const size_t koff0 = (bT + rg0) * 2048 + 1024 + h * DHEAD + sc0 * 8;
    const size_t koff1 = (bT + rg1) * 2048 + 1024 + h * DHEAD + sc1 * 8;
    const short* const pKh0 = qkhi + koff0;
    const short* const pKh1 = qkhi + koff1;
    const short* const pKl0 = qklo + koff0;
    const short* const pKl1 = qklo + koff1;
    const short* const pV0 = vt + ((size_t)((b * NHEAD + h) * DHEAD) + rg0) * T_SEQ + sc0 * 8;
    const short* const pV1 = vt + ((size_t)((b * NHEAD + h) * DHEAD) + rg1) * T_SEQ + sc1 * 8;

    const int psBase = 16384 + w * 1024;
    const int pwChunk = (lg >> 1);
    const int pwIntra = (lg & 1) * 4;

    for (int half = 0; half < 2; ++half) {
        const int xi = half ? (31 - p) : p;
        const int qw = xi * 64 + w * 16;
        const int nsteps = xi + 1;

        __syncthreads();

        bf16x8 qhi[2], qlo[2];
        #pragma unroll
        for (int kk = 0; kk < 2; ++kk) {
            size_t off = (bT + qw + lr) * 2048 + h * DHEAD + kk * 32 + lg * 8;
            qhi[kk] = *(const bf16x8*)(qkhi + off);
            qlo[kk] = *(const bf16x8*)(qklo + off);
        }
        __builtin_amdgcn_sched_barrier(0);

        gload16(pKh0, dK0);
        gload16(pKh1, dK1);
        gload16(pKl0, dK0 + 4096);
        gload16(pKl1, dK1 + 4096);
        gload16(pV0, dK0 + 8192);
        gload16(pV1, dK1 + 8192);
        {
            int j1 = (nsteps > 1) ? 64 : 0;
            gload16(pV0 + j1, dK0 + 12288);
            gload16(pV1 + j1, dK1 + 12288);
        }

        f32x4 O[4];
        #pragma unroll
        for (int dt = 0; dt < 4; ++dt)
            O[dt] = (f32x4){0.f, 0.f, 0.f, 0.f};
        float mrow = -3.0e38f;
        float lrow = 0.f;

        for (int t = 0; t < nsteps; ++t) {
            const int j0 = t * 64;
            asm volatile("s_waitcnt vmcnt(2)" ::: "memory");
            __builtin_amdgcn_s_barrier();
            __builtin_amdgcn_sched_barrier(0);
            const int vbase = 8192 + (t & 1) * 4096;

            f32x4 St[4];
            __builtin_amdgcn_s_setprio(1);
            #pragma unroll
            for (int ct = 0; ct < 4; ++ct) {
                f32x4 s = (f32x4){0.f, 0.f, 0.f, 0.f};
                #pragma unroll
                for (int kk = 0; kk < 2; ++kk) {
                    int j  = ct * 16 + lr;
                    int ck = kk * 4 + lg;
                    int idx = j * 64 + ((ck ^ (j & 7)) << 3);
                    bf16x8 kh8 = *(bf16x8*)&smem[idx];
                    bf16x8 kl8 = *(bf16x8*)&smem[4096 + idx];
                    s = __builtin_amdgcn_mfma_f32_16x16x32_bf16(kh8, qhi[kk], s, 0, 0, 0);
                    s = __builtin_amdgcn_mfma_f32_16x16x32_bf16(kh8, qlo[kk], s, 0, 0, 0);
                    s = __builtin_amdgcn_mfma_f32_16x16x32_bf16(kl8, qhi[kk], s, 0, 0, 0);
                }
                St[ct] = s;
            }
            __builtin_amdgcn_s_setprio(0);
            __builtin_amdgcn_sched_barrier(0);
            __builtin_amdgcn_s_barrier();      // all waves' K ds_reads complete
            __builtin_amdgcn_sched_barrier(0);
            if (t + 1 < nsteps) {              // early K(t+1): flies under SM+PV
                size_t ko = (size_t)(t + 1) * 131072;
                gload16(pKh0 + ko, dK0);
                gload16(pKh1 + ko, dK1);
                gload16(pKl0 + ko, dK0 + 4096);
                gload16(pKl1 + ko, dK1 + 4096);
            }

            #pragma unroll
            for (int ct = 0; ct < 4; ++ct) {
                if (j0 + ct * 16 + 15 > qw) {
                    #pragma unroll
                    for (int r = 0; r < 4; ++r) {
                        int jabs = j0 + ct * 16 + lg * 4 + r;
                        St[ct][r] = (jabs <= qw + lr) ? St[ct][r] : -3.0e38f;
                    }
                }
            }

            float tm = fmaxf(fmaxf(fmaxf(St[0][0], St[0][1]), fmaxf(St[0][2], St[0][3])),
                             fmaxf(fmaxf(St[1][0], St[1][1]), fmaxf(St[1][2], St[1][3])));
            tm = fmaxf(tm, fmaxf(fmaxf(fmaxf(St[2][0], St[2][1]), fmaxf(St[2][2], St[2][3])),
                                 fmaxf(fmaxf(St[3][0], St[3][1]), fmaxf(St[3][2], St[3][3]))));
            tm = fmaxf(tm, __shfl_xor(tm, 16));
            tm = fmaxf(tm, __shfl_xor(tm, 32));

            if (__any(tm > mrow)) {
                float mnew  = fmaxf(mrow, tm);
                float alpha = __builtin_amdgcn_exp2f(mrow - mnew);
                mrow = mnew;
                lrow *= alpha;
                #pragma unroll
                for (int r = 0; r < 4; ++r) {
                    float aO = __shfl(alpha, lg * 4 + r);
                    #pragma unroll
                    for (int dt = 0; dt < 4; ++dt)
                        O[dt][r] *= aO;
                }
            }

            #pragma unroll
            for (int ct = 0; ct < 4; ++ct) {
                float p0 = __builtin_amdgcn_exp2f(St[ct][0] - mrow);
                float p1 = __builtin_amdgcn_exp2f(St[ct][1] - mrow);
                float p2 = __builtin_amdgcn_exp2f(St[ct][2] - mrow);
                float p3 = __builtin_amdgcn_exp2f(St[ct][3] - mrow);
                lrow += (p0 + p1) + (p2 + p3);
                unsigned u0 = (__builtin_bit_cast(unsigned, p0) >> 16) |
                              (__builtin_bit_cast(unsigned, p1) & 0xFFFF0000u);
                unsigned u1 = (__builtin_bit_cast(unsigned, p2) >> 16) |
                              (__builtin_bit_cast(unsigned, p3) & 0xFFFF0000u);
                int chunk = ct * 2 + pwChunk;
                int sidx = psBase + lr * 64 + ((chunk ^ (lr & 7)) << 3) + pwIntra;
                uint2 uu; uu.x = u0; uu.y = u1;
                *(uint2*)&smem[sidx] = uu;
            }

            __builtin_amdgcn_wave_barrier();

            bf16x8 pa[2];
            #pragma unroll
            for (int jk = 0; jk < 2; ++jk) {
                int ck = jk * 4 + lg;
                pa[jk] = *(bf16x8*)&smem[psBase + lr * 64 + ((ck ^ (lr & 7)) << 3)];
            }
            __builtin_amdgcn_s_setprio(1);
            #pragma unroll
            for (int dt = 0; dt < 4; ++dt) {
                #pragma unroll
                for (int jk = 0; jk < 2; ++jk) {
                    int d  = dt * 16 + lr;
                    int ck = jk * 4 + lg;
                    bf16x8 vb = *(bf16x8*)&smem[vbase + d * 64 + ((ck ^ (d & 7)) << 3)];
                    O[dt] = __builtin_amdgcn_mfma_f32_16x16x32_bf16(pa[jk], vb, O[dt], 0, 0, 0);
                }
            }
            __builtin_amdgcn_s_setprio(0);

            __builtin_amdgcn_sched_barrier(0);
            __builtin_amdgcn_s_barrier();      // all PV reads of V(t) done
            __builtin_amdgcn_sched_barrier(0);

            if (t + 1 < nsteps) {              // V(t+2) into buf (t&1)
                int jv = (t + 2 < nsteps) ? (t + 2) : (nsteps - 1);
                short* const dV = &smem[8192 + (t & 1) * 4096];
                gload16(pV0 + jv * 64, dV + (w * 128) * 8);
                gload16(pV1 + jv * 64, dV + (w * 128 + 64) * 8);
            }
        }

        float lsum = lrow + __shfl_xor(lrow, 16);
        lsum += __shfl_xor(lsum, 32);
        #pragma unroll
        for (int r = 0; r < 4; ++r) {
            float lO = __shfl(lsum, lg * 4 + r);
            float inv = 1.0f / lO;
            int row = qw + lg * 4 + r;
            #pragma unroll
            for (int dt = 0; dt < 4; ++dt) {
                int col = h * DHEAD + dt * 16 + lr;
                ctxb[(size_t)(b * T_SEQ + row) * CEMB + col] = (short)f2bf(O[dt][r] * inv);
            }
        }
    }
}

// ---------------------------------------------------------------------------
extern "C" void kernel_launch(void* const* d_in, const int* in_sizes, int n_in,
                              void* d_out, int out_size, void* d_ws, size_t ws_size,
                              hipStream_t stream)
{
    const float* x    = (const float*)d_in[0];
    const float* Wqkv = (const float*)d_in[1];
    const float* bqkv = (const float*)d_in[2];
    const float* Wo   = (const float*)d_in[3];
    const float* bo   = (const float*)d_in[4];
    float* out = (float*)d_out;

    // Workspace (110 MB):
    //  0-32  qkhi    32-64 qklo    64-80 Vt    80-96 ctxb    96-110 weights
    char* ws = (char*)d_ws;
    short* qkhi = (short*)ws;
    short* qklo = (short*)(ws + (size_t)(32u << 20));
    short* Vt   = (short*)(ws + (size_t)(64u << 20));
    short* ctxb = (short*)(ws + (size_t)(80u << 20));
    short* WhiT = (short*)(ws + (size_t)(96u << 20));
    short* WloT = (short*)(ws + (size_t)(102u << 20));
    short* WoT  = (short*)(ws + (size_t)(108u << 20));

    // 1) weight transpose+split
    transpose_split_kernel<<<dim3(48, 16), 256, 0, stream>>>(Wqkv, 3 * CEMB, WhiT, WloT);
    transpose_split_kernel<<<dim3(16, 16), 256, 0, stream>>>(Wo, CEMB, WoT, nullptr);

    // 2) qk = x @ Wqk + b  -> split hi/lo bf16, q cols pre-scaled (XCD swizzle)
    gemm_qk_kernel<<<dim3(1024), 256, 0, stream>>>(
        x, WhiT, WloT, bqkv, qkhi, qklo, CEMB);

    // 3) V = x @ Wv + bv -> Vt directly (transposed epilogue, XCD swizzle)
    gemm_v_kernel<<<dim3(512), 256, 0, stream>>>(
        x, WhiT + (size_t)2048 * 1024, bqkv + 2048, Vt, CEMB);

    // 4) causal MFMA flash attention -> ctx bf16 (early-K pipeline)
    attn_mfma_kernel<<<dim3(1024), 256, 0, stream>>>(qkhi, qklo, Vt, ctxb);

    // 5) out = ctx @ Wo + bo  (fp32 out, counted-vmcnt pipeline)
    gemm_proj_kernel<<<dim3(8, 64), 256, 0, stream>>>(
        ctxb, WoT, bo, out, CEMB, CEMB);
}